// Round 10
// baseline (904.767 us; speedup 1.0000x reference)
//
#include <hip/hip_runtime.h>
#include <stdint.h>
#include <math.h>

#define K_CODES 4096
#define DIM 128
#define N_FLAT 32768      // 32 * 32 * 32
#define HW 1024           // 32*32 spatial per batch

// output offsets (floats): quantized_st, loss, perplexity, encodings, indices
#define OFF_Q    0
#define OFF_LOSS 4194304
#define OFF_PERP 4194305
#define OFF_ENC  4194306
#define OFF_IDX  138412034

// workspace offsets (bytes)
#define WS_PACKED 0                        // 32768 * 8
#define WS_COUNTS 262144                   // 4096 * 4
#define WS_WSQ    278528                   // 4096 * 4
#define WS_XSQ    294912                   // 32768 * 4
#define WS_PART   425984                   // 1024 * 4
#define WS_XHL    430080                   // 32768 rows * 256 f16 = 16 MB
#define WS_WHL    (WS_XHL + 16777216)      // 4096 rows * 256 f16 = 2 MB

typedef _Float16 f16x8 __attribute__((ext_vector_type(8)));
typedef float    f32x4 __attribute__((ext_vector_type(4)));

// f16 plane rows: [row][0:128]=h, [row][128:256]=l (512 B). Exact pow2
// scales x*32, w*1024 -> acc = 2^15*dot, unscale by 2^-14 is exact.

// ---------------- K1: w_sq + counts zero. grid 1024 x 256 (4 waves = 4 k) --
__global__ __launch_bounds__(256) void wsq_kernel(const float* __restrict__ w,
                                                  float* __restrict__ wsq,
                                                  float* __restrict__ counts) {
    int wave = threadIdx.x >> 6, lane = threadIdx.x & 63;
    int k = blockIdx.x * 4 + wave;
    float a = w[k * DIM + lane];
    float b = w[k * DIM + lane + 64];
    float s = a * a + b * b;
    #pragma unroll
    for (int o = 32; o > 0; o >>= 1) s += __shfl_down(s, o, 64);
    if (lane == 0) { wsq[k] = s; counts[k] = 0.f; }
}

// ---------------- K2: w -> f16 h/l planes ----------------------------------
__global__ __launch_bounds__(256) void wplanes_kernel(const float* __restrict__ w,
                                                      _Float16* __restrict__ whl) {
    int T = blockIdx.x * 256 + threadIdx.x;
    int k = T >> 2, seg = T & 3;
    const float* wp = w + (size_t)k * DIM + seg * 32;
    _Float16* row = whl + (size_t)k * 256;
    #pragma unroll
    for (int q = 0; q < 4; ++q) {
        float4 a = *(const float4*)(wp + q * 8);
        float4 b = *(const float4*)(wp + q * 8 + 4);
        float vv[8] = {a.x, a.y, a.z, a.w, b.x, b.y, b.z, b.w};
        f16x8 hv, lv;
        #pragma unroll
        for (int j = 0; j < 8; ++j) {
            float v = 1024.0f * vv[j];
            _Float16 h = (_Float16)v;
            _Float16 l = (_Float16)(v - (float)h);
            hv[j] = h; lv[j] = l;
        }
        *(f16x8*)(row + seg * 32 + q * 8) = hv;
        *(f16x8*)(row + 128 + seg * 32 + q * 8) = lv;
    }
}

// ---------------- K3: x -> planes + x_sq + packed init (fused) -------------
__global__ __launch_bounds__(256) void xprep_kernel(const float* __restrict__ x,
                                                    _Float16* __restrict__ xhl,
                                                    float* __restrict__ xsq,
                                                    unsigned long long* __restrict__ packed) {
    __shared__ float xt[128 * 65];            // [c][n], pad 65
    const int t = threadIdx.x;
    const int n0 = blockIdx.x * 64;
    const int b = n0 >> 10, hw0 = n0 & 1023;
    const float* xg = x + (size_t)b * (DIM * HW) + hw0;
    #pragma unroll
    for (int i = 0; i < 16; ++i) {
        int idx = i * 256 + t;                // 4096 float2
        int c = idx >> 5, n2 = (idx & 31) << 1;
        float2 v = *(const float2*)(xg + c * HW + n2);
        xt[c * 65 + n2] = v.x;
        xt[c * 65 + n2 + 1] = v.y;
    }
    __syncthreads();
    if (t < 64) {
        packed[n0 + t] = ~0ull;
        float s = 0.f;                        // strict c order, fp32 (== ref path)
        #pragma unroll
        for (int c = 0; c < DIM; ++c) {
            float v = xt[c * 65 + t];
            s = fmaf(v, v, s);
        }
        xsq[n0 + t] = s;
    }
    const int n = t >> 2, seg = t & 3;
    _Float16* row = xhl + (size_t)(n0 + n) * 256;
    #pragma unroll
    for (int q = 0; q < 4; ++q) {
        f16x8 hv, lv;
        #pragma unroll
        for (int j = 0; j < 8; ++j) {
            float v = 32.0f * xt[(seg * 32 + q * 8 + j) * 65 + n];
            _Float16 h = (_Float16)v;
            _Float16 l = (_Float16)(v - (float)h);
            hv[j] = h; lv[j] = l;
        }
        *(f16x8*)(row + seg * 32 + q * 8) = hv;
        *(f16x8*)(row + 128 + seg * 32 + q * 8) = lv;
    }
}

// ---------------- K4: MFMA distance GEMM + split-K argmin ------------------
// grid (256 n-tiles, 8 k-supertiles), block 256 = 4 waves 2x2. Each block:
// 128n x 512k as 4 sub-tiles of 128k, d chunked by 32. R8-style staging
// (load->LDS within the chunk: all K-loop reads are L1/L2-hot, latency is
// covered by 3-4 resident blocks -- R9's register prefetch pushed VGPR to
// 160 and HALVED residency, a net loss). Argmin = per-thread running best
// across all ks, one shuffle-reduce + atomicMin at the end. wsq in regs.
__global__ __launch_bounds__(256) void dist_argmin(
    const _Float16* __restrict__ xhl, const _Float16* __restrict__ whl,
    const float* __restrict__ wsq, const float* __restrict__ xsq,
    unsigned long long* __restrict__ packed, float* __restrict__ enc)
{
    __shared__ __align__(16) _Float16 xl[128 * 72];   // row stride 144 B
    __shared__ __align__(16) _Float16 wl[128 * 72];
    __shared__ float xsq_s[128];
    __shared__ unsigned long long red[128][2];

    const int tid  = threadIdx.x;
    const int lane = tid & 63, wave = tid >> 6;
    const int lq   = lane & 15, quad = lane >> 4;
    const int wn0  = (wave >> 1) * 64, wk0 = (wave & 1) * 64;
    const int n0   = blockIdx.x * 128;
    const int kbase = blockIdx.y * 512;

    const int sr = tid >> 3, sh = (tid >> 2) & 1, sq = tid & 3;
    const int gsub = sh * 128 + sq * 8;       // within-row f16 offset (h/l, seg)
    const int lsub = sh * 32 + sq * 8;

    const _Float16* xbase = xhl + (size_t)n0 * 256;

    if (tid < 128) xsq_s[tid] = xsq[n0 + tid];

    // ---- zero-fill 128n x 512k encodings rect (float4 +2 shift; 2-float
    // spill into next row is zero-over-zero; last row's spill lands in idx
    // region, later overwritten by combine in stream order) -----------------
    {
        float* ebase = enc + (size_t)n0 * K_CODES + kbase;
        float4 z4; z4.x = z4.y = z4.z = z4.w = 0.f;
        #pragma unroll 8
        for (int i = 0; i < 64; ++i) {
            int idx = i * 256 + tid;
            int r = idx >> 7, c4 = idx & 127;
            *(float4*)(ebase + (size_t)r * K_CODES + 2 + c4 * 4) = z4;
        }
        if (tid < 128) {
            float2 z2; z2.x = 0.f; z2.y = 0.f;
            *(float2*)(ebase + (size_t)tid * K_CODES) = z2;
        }
    }

    float bestf[4][4];
    int   bestk[4][4];
    #pragma unroll
    for (int i = 0; i < 4; ++i)
        #pragma unroll
        for (int j = 0; j < 4; ++j) { bestf[i][j] = 3.4e38f; bestk[i][j] = 0; }

    for (int ks = 0; ks < 4; ++ks) {
        const int k0 = kbase + ks * 128;
        const _Float16* wbase = whl + (size_t)k0 * 256;
        // wsq for this thread's 4 k's -> registers (quad-broadcast loads)
        float wsq_r[4];
        #pragma unroll
        for (int ki = 0; ki < 4; ++ki)
            wsq_r[ki] = wsq[k0 + wk0 + ki * 16 + lq];

        f32x4 acc[4][4];
        #pragma unroll
        for (int i = 0; i < 4; ++i)
            #pragma unroll
            for (int j = 0; j < 4; ++j)
                acc[i][j] = (f32x4){0.f, 0.f, 0.f, 0.f};

        #pragma unroll
        for (int c0 = 0; c0 < 4; ++c0) {
            __syncthreads();                  // prev chunk's frag reads done
            #pragma unroll
            for (int i = 0; i < 4; ++i) {
                int r = sr + i * 32;
                int goff = r * 256 + c0 * 32 + gsub;
                int loff = r * 72 + lsub;
                *(f16x8*)(xl + loff) = *(const f16x8*)(xbase + goff);
                *(f16x8*)(wl + loff) = *(const f16x8*)(wbase + goff);
            }
            __syncthreads();

            f16x8 ah[4], al[4], bh[4], bl[4];
            #pragma unroll
            for (int i = 0; i < 4; ++i) {
                int xrow = (wn0 + i * 16 + lq) * 72 + quad * 8;
                ah[i] = *(const f16x8*)(xl + xrow);
                al[i] = *(const f16x8*)(xl + xrow + 32);
                int wrow = (wk0 + i * 16 + lq) * 72 + quad * 8;
                bh[i] = *(const f16x8*)(wl + wrow);
                bl[i] = *(const f16x8*)(wl + wrow + 32);
            }
            #pragma unroll
            for (int ki = 0; ki < 4; ++ki)
                #pragma unroll
                for (int ni = 0; ni < 4; ++ni) {
                    acc[ni][ki] = __builtin_amdgcn_mfma_f32_16x16x32_f16(
                        ah[ni], bh[ki], acc[ni][ki], 0, 0, 0);
                    acc[ni][ki] = __builtin_amdgcn_mfma_f32_16x16x32_f16(
                        ah[ni], bl[ki], acc[ni][ki], 0, 0, 0);
                    acc[ni][ki] = __builtin_amdgcn_mfma_f32_16x16x32_f16(
                        al[ni], bh[ki], acc[ni][ki], 0, 0, 0);
                }
        }

        // ---- running-best update for this 128k sub-tile -------------------
        #pragma unroll
        for (int ni = 0; ni < 4; ++ni) {
            #pragma unroll
            for (int rg = 0; rg < 4; ++rg) {
                int rowl = wn0 + ni * 16 + quad * 4 + rg;
                float xr = xsq_s[rowl];
                #pragma unroll
                for (int ki = 0; ki < 4; ++ki) {
                    float t = xr - acc[ni][ki][rg] * 6.103515625e-05f; // 2^-14
                    t += wsq_r[ki];
                    t += 1e-8f;
                    if (t < bestf[ni][rg]) {
                        bestf[ni][rg] = t;
                        bestk[ni][rg] = k0 + wk0 + ki * 16 + lq;
                    }
                }
            }
        }
    }

    // ---- final reduce: pack, shuffle over the 16 lq lanes, atomicMin ------
    #pragma unroll
    for (int ni = 0; ni < 4; ++ni) {
        #pragma unroll
        for (int rg = 0; rg < 4; ++rg) {
            int rowl = wn0 + ni * 16 + quad * 4 + rg;
            unsigned u = __float_as_uint(bestf[ni][rg]);
            u = (u & 0x80000000u) ? ~u : (u | 0x80000000u);
            unsigned long long p =
                ((unsigned long long)u << 32) | (unsigned)bestk[ni][rg];
            #pragma unroll
            for (int m = 1; m < 16; m <<= 1) {
                unsigned long long o = __shfl_xor(p, m, 64);
                if (o < p) p = o;
            }
            if (lq == 0) red[rowl][wave & 1] = p;
        }
    }
    __syncthreads();
    if (tid < 128) {
        unsigned long long a = red[tid][0], b = red[tid][1];
        atomicMin(&packed[n0 + tid], a < b ? a : b);
    }
}

// ---------------- K5: combine -> indices, one-hot 1.0, counts ---------------
__global__ __launch_bounds__(256) void combine(
    const unsigned long long* __restrict__ packed,
    float* __restrict__ idxf, float* __restrict__ enc,
    float* __restrict__ counts)
{
    int n = blockIdx.x * 256 + threadIdx.x;
    unsigned k = (unsigned)(packed[n] & 0xFFFFFFFFu);
    idxf[n] = (float)k;
    enc[(size_t)n * K_CODES + k] = 1.0f;
    atomicAdd(&counts[k], 1.0f);
}

// ---------------- K6: gather -> quantized_st (NCHW) + per-block loss partial
__global__ __launch_bounds__(256) void quantize_loss(
    const float* __restrict__ x, const float* __restrict__ w,
    const float* __restrict__ idxf, float* __restrict__ outq,
    float* __restrict__ part)
{
    const int base4 = (blockIdx.x * 256 + threadIdx.x) * 4;
    float s = 0.f;
    #pragma unroll
    for (int i = 0; i < 4; ++i) {
        int e  = base4 + i * 1048576;      // NCHW element index (x4 aligned)
        int hw = e & 1023;
        int c  = (e >> 10) & 127;
        int b  = e >> 17;
        int n  = (b << 10) | hw;           // multiple of 4
        float4 xv = *(const float4*)(x + e);
        float4 kf = *(const float4*)(idxf + n);
        float q0 = w[(int)kf.x * DIM + c];
        float q1 = w[(int)kf.y * DIM + c];
        float q2 = w[(int)kf.z * DIM + c];
        float q3 = w[(int)kf.w * DIM + c];
        float4 df; df.x = q0 - xv.x; df.y = q1 - xv.y;
                   df.z = q2 - xv.z; df.w = q3 - xv.w;
        float4 o;  o.x = xv.x + df.x; o.y = xv.y + df.y;
                   o.z = xv.z + df.z; o.w = xv.w + df.w;
        *(float4*)(outq + e) = o;
        s = fmaf(df.x, df.x, s);
        s = fmaf(df.y, df.y, s);
        s = fmaf(df.z, df.z, s);
        s = fmaf(df.w, df.w, s);
    }
    #pragma unroll
    for (int o = 32; o > 0; o >>= 1) s += __shfl_down(s, o, 64);
    __shared__ float ls[4];
    if ((threadIdx.x & 63) == 0) ls[threadIdx.x >> 6] = s;
    __syncthreads();
    if (threadIdx.x == 0) part[blockIdx.x] = ls[0] + ls[1] + ls[2] + ls[3];
}

// ---------------- K7: loss (from partials) + perplexity ---------------------
__global__ __launch_bounds__(256) void finalize(
    const float* __restrict__ counts, const float* __restrict__ part,
    float* __restrict__ out)
{
    __shared__ float sh[512];
    float h = 0.f;
    for (int k = threadIdx.x; k < K_CODES; k += 256) {
        float p = counts[k] * (1.0f / N_FLAT);
        h += p * logf(p + 1e-10f);
    }
    float s = 0.f;
    for (int i = threadIdx.x; i < 1024; i += 256) s += part[i];
    sh[threadIdx.x] = h;
    sh[256 + threadIdx.x] = s;
    __syncthreads();
    #pragma unroll
    for (int st = 128; st > 0; st >>= 1) {
        if (threadIdx.x < st) {
            sh[threadIdx.x] += sh[threadIdx.x + st];
            sh[256 + threadIdx.x] += sh[256 + threadIdx.x + st];
        }
        __syncthreads();
    }
    if (threadIdx.x == 0) {
        float perp = expf(-sh[0]);
        float loss = 1.25f * (sh[256] / 4194304.0f);
        if (isnan(loss) || isinf(loss)) loss = 0.1f;
        out[OFF_LOSS] = loss;
        out[OFF_PERP] = perp;
    }
}

extern "C" void kernel_launch(void* const* d_in, const int* in_sizes, int n_in,
                              void* d_out, int out_size, void* d_ws, size_t ws_size,
                              hipStream_t stream) {
    const float* x = (const float*)d_in[0];   // [32,128,32,32] fp32 NCHW
    const float* w = (const float*)d_in[1];   // [4096,128] fp32
    float* out = (float*)d_out;
    char* ws = (char*)d_ws;

    unsigned long long* packed = (unsigned long long*)(ws + WS_PACKED);
    float* counts = (float*)(ws + WS_COUNTS);
    float* wsq    = (float*)(ws + WS_WSQ);
    float* xsq    = (float*)(ws + WS_XSQ);
    float* part   = (float*)(ws + WS_PART);
    _Float16* xhl = (_Float16*)(ws + WS_XHL);
    _Float16* whl = (_Float16*)(ws + WS_WHL);

    wsq_kernel<<<K_CODES / 4, 256, 0, stream>>>(w, wsq, counts);
    wplanes_kernel<<<K_CODES * 4 / 256, 256, 0, stream>>>(w, whl);
    xprep_kernel<<<N_FLAT / 64, 256, 0, stream>>>(x, xhl, xsq, packed);

    dim3 g2(256, 8);
    dist_argmin<<<g2, 256, 0, stream>>>(xhl, whl, wsq, xsq, packed,
                                        out + OFF_ENC);

    combine<<<N_FLAT / 256, 256, 0, stream>>>(packed, out + OFF_IDX,
                                              out + OFF_ENC, counts);

    quantize_loss<<<1024, 256, 0, stream>>>(x, w, out + OFF_IDX,
                                            out + OFF_Q, part);

    finalize<<<1, 256, 0, stream>>>(counts, part, out);
}

// Round 11
// 848.092 us; speedup vs baseline: 1.0668x; 1.0668x over previous
//
#include <hip/hip_runtime.h>
#include <stdint.h>
#include <math.h>

#define K_CODES 4096
#define DIM 128
#define N_FLAT 32768      // 32 * 32 * 32
#define HW 1024           // 32*32 spatial per batch

// output offsets (floats): quantized_st, loss, perplexity, encodings, indices
#define OFF_Q    0
#define OFF_LOSS 4194304
#define OFF_PERP 4194305
#define OFF_ENC  4194306
#define OFF_IDX  138412034

// workspace offsets (bytes)
#define WS_PACKED 0                        // 32768 * 8
#define WS_COUNTS 262144                   // 4096 * 4
#define WS_WSQ    278528                   // 4096 * 4
#define WS_XSQ    294912                   // 32768 * 4
#define WS_PART   425984                   // 1024 * 4
#define WS_XHL    430080                   // 32768 rows * 256 f16 = 16 MB
#define WS_WHL    (WS_XHL + 16777216)      // 4096 rows * 256 f16 = 2 MB

typedef _Float16 f16x8 __attribute__((ext_vector_type(8)));
typedef float    f32x4 __attribute__((ext_vector_type(4)));

// f16 plane rows: [row][0:128]=h, [row][128:256]=l (512 B). Exact pow2
// scales x*32, w*1024 -> acc = 2^15*dot, unscale by 2^-14 is exact.
//
// NOTE (R9/R10 post-mortem): do NOT hoist the argmin running-best out of
// the ks loop and do NOT register-prefetch global chunks — both push VGPR
// to 160 (64 acc + 64 frag + 32 best) and halve residency. The per-ks
// epilogue below keeps VGPR ~128 and was the session's best (845 us).

// ---------------- K1: w_sq + counts zero. grid 1024 x 256 (4 waves = 4 k) --
__global__ __launch_bounds__(256) void wsq_kernel(const float* __restrict__ w,
                                                  float* __restrict__ wsq,
                                                  float* __restrict__ counts) {
    int wave = threadIdx.x >> 6, lane = threadIdx.x & 63;
    int k = blockIdx.x * 4 + wave;
    float a = w[k * DIM + lane];
    float b = w[k * DIM + lane + 64];
    float s = a * a + b * b;
    #pragma unroll
    for (int o = 32; o > 0; o >>= 1) s += __shfl_down(s, o, 64);
    if (lane == 0) { wsq[k] = s; counts[k] = 0.f; }
}

// ---------------- K2: w -> f16 h/l planes ----------------------------------
__global__ __launch_bounds__(256) void wplanes_kernel(const float* __restrict__ w,
                                                      _Float16* __restrict__ whl) {
    int T = blockIdx.x * 256 + threadIdx.x;
    int k = T >> 2, seg = T & 3;
    const float* wp = w + (size_t)k * DIM + seg * 32;
    _Float16* row = whl + (size_t)k * 256;
    #pragma unroll
    for (int q = 0; q < 4; ++q) {
        float4 a = *(const float4*)(wp + q * 8);
        float4 b = *(const float4*)(wp + q * 8 + 4);
        float vv[8] = {a.x, a.y, a.z, a.w, b.x, b.y, b.z, b.w};
        f16x8 hv, lv;
        #pragma unroll
        for (int j = 0; j < 8; ++j) {
            float v = 1024.0f * vv[j];
            _Float16 h = (_Float16)v;
            _Float16 l = (_Float16)(v - (float)h);
            hv[j] = h; lv[j] = l;
        }
        *(f16x8*)(row + seg * 32 + q * 8) = hv;
        *(f16x8*)(row + 128 + seg * 32 + q * 8) = lv;
    }
}

// ---------------- K3: x -> planes + x_sq + packed init (fused) -------------
__global__ __launch_bounds__(256) void xprep_kernel(const float* __restrict__ x,
                                                    _Float16* __restrict__ xhl,
                                                    float* __restrict__ xsq,
                                                    unsigned long long* __restrict__ packed) {
    __shared__ float xt[128 * 65];            // [c][n], pad 65
    const int t = threadIdx.x;
    const int n0 = blockIdx.x * 64;
    const int b = n0 >> 10, hw0 = n0 & 1023;
    const float* xg = x + (size_t)b * (DIM * HW) + hw0;
    #pragma unroll
    for (int i = 0; i < 16; ++i) {
        int idx = i * 256 + t;                // 4096 float2
        int c = idx >> 5, n2 = (idx & 31) << 1;
        float2 v = *(const float2*)(xg + c * HW + n2);
        xt[c * 65 + n2] = v.x;
        xt[c * 65 + n2 + 1] = v.y;
    }
    __syncthreads();
    if (t < 64) {
        packed[n0 + t] = ~0ull;
        float s = 0.f;                        // strict c order, fp32 (== ref path)
        #pragma unroll
        for (int c = 0; c < DIM; ++c) {
            float v = xt[c * 65 + t];
            s = fmaf(v, v, s);
        }
        xsq[n0 + t] = s;
    }
    const int n = t >> 2, seg = t & 3;
    _Float16* row = xhl + (size_t)(n0 + n) * 256;
    #pragma unroll
    for (int q = 0; q < 4; ++q) {
        f16x8 hv, lv;
        #pragma unroll
        for (int j = 0; j < 8; ++j) {
            float v = 32.0f * xt[(seg * 32 + q * 8 + j) * 65 + n];
            _Float16 h = (_Float16)v;
            _Float16 l = (_Float16)(v - (float)h);
            hv[j] = h; lv[j] = l;
        }
        *(f16x8*)(row + seg * 32 + q * 8) = hv;
        *(f16x8*)(row + 128 + seg * 32 + q * 8) = lv;
    }
}

// ---------------- K4: MFMA distance GEMM + split-K argmin ------------------
// grid (256 n-tiles, 8 k-supertiles), block 256 = 4 waves 2x2. Each block:
// 128n x 512k via 4 sub-tiles of 128k. Wave tile 64x64 = 4x4
// mfma_f32_16x16x32_f16, 3 MFMAs per tile (hH,hL,lH Dekker split).
// Layouts per m89/m120. Per-ks epilogue (keeps VGPR ~128, 4 blocks/CU).
__global__ __launch_bounds__(256) void dist_argmin(
    const _Float16* __restrict__ xhl, const _Float16* __restrict__ whl,
    const float* __restrict__ wsq, const float* __restrict__ xsq,
    unsigned long long* __restrict__ packed, float* __restrict__ enc)
{
    __shared__ __align__(16) _Float16 xl[128 * 72];   // row stride 144 B
    __shared__ __align__(16) _Float16 wl[128 * 72];
    __shared__ float xsq_s[128], wsq_s[128];
    __shared__ unsigned long long red[128][2];

    const int tid  = threadIdx.x;
    const int lane = tid & 63, wave = tid >> 6;
    const int lq   = lane & 15, quad = lane >> 4;
    const int wn0  = (wave >> 1) * 64, wk0 = (wave & 1) * 64;
    const int n0   = blockIdx.x * 128;
    const int kbase = blockIdx.y * 512;

    const int sr = tid >> 3, sh = (tid >> 2) & 1, sq = tid & 3;

    // ---- zero-fill 128n x 512k encodings rect (float4, +2 shift for 16B
    // alignment; 2-float spill into next row is zero-over-zero benign; last
    // row's spill into idx region is overwritten later by combine) ----------
    {
        float* ebase = enc + (size_t)n0 * K_CODES + kbase;
        float4 z4; z4.x = z4.y = z4.z = z4.w = 0.f;
        #pragma unroll 8
        for (int i = 0; i < 64; ++i) {
            int idx = i * 256 + tid;
            int r = idx >> 7, c4 = idx & 127;
            *(float4*)(ebase + (size_t)r * K_CODES + 2 + c4 * 4) = z4;
        }
        if (tid < 128) {
            float2 z2; z2.x = 0.f; z2.y = 0.f;
            *(float2*)(ebase + (size_t)tid * K_CODES) = z2;
        }
    }

    if (tid < 128) xsq_s[tid] = xsq[n0 + tid];

    const _Float16* xbase = xhl + (size_t)n0 * 256;

    for (int ks = 0; ks < 4; ++ks) {
        const int k0 = kbase + ks * 128;
        if (tid < 128) wsq_s[tid] = wsq[k0 + tid];   // ordered by c0=0 barrier
        const _Float16* wbase = whl + (size_t)k0 * 256;

        f32x4 acc[4][4];
        #pragma unroll
        for (int i = 0; i < 4; ++i)
            #pragma unroll
            for (int j = 0; j < 4; ++j)
                acc[i][j] = (f32x4){0.f, 0.f, 0.f, 0.f};

        #pragma unroll
        for (int c0 = 0; c0 < 4; ++c0) {
            __syncthreads();
            #pragma unroll
            for (int i = 0; i < 4; ++i) {
                int r = sr + i * 32;
                int goff = r * 256 + sh * 128 + c0 * 32 + sq * 8;
                int loff = r * 72 + sh * 32 + sq * 8;
                *(f16x8*)(xl + loff) = *(const f16x8*)(xbase + goff);
                *(f16x8*)(wl + loff) = *(const f16x8*)(wbase + goff);
            }
            __syncthreads();

            f16x8 ah[4], al[4], bh[4], bl[4];
            #pragma unroll
            for (int i = 0; i < 4; ++i) {
                int xrow = (wn0 + i * 16 + lq) * 72 + quad * 8;
                ah[i] = *(const f16x8*)(xl + xrow);
                al[i] = *(const f16x8*)(xl + xrow + 32);
                int wrow = (wk0 + i * 16 + lq) * 72 + quad * 8;
                bh[i] = *(const f16x8*)(wl + wrow);
                bl[i] = *(const f16x8*)(wl + wrow + 32);
            }
            #pragma unroll
            for (int ki = 0; ki < 4; ++ki)
                #pragma unroll
                for (int ni = 0; ni < 4; ++ni) {
                    acc[ni][ki] = __builtin_amdgcn_mfma_f32_16x16x32_f16(
                        ah[ni], bh[ki], acc[ni][ki], 0, 0, 0);
                    acc[ni][ki] = __builtin_amdgcn_mfma_f32_16x16x32_f16(
                        ah[ni], bl[ki], acc[ni][ki], 0, 0, 0);
                    acc[ni][ki] = __builtin_amdgcn_mfma_f32_16x16x32_f16(
                        al[ni], bh[ki], acc[ni][ki], 0, 0, 0);
                }
        }

        // ---- epilogue: distances + argmin for this 128k sub-tile ----------
        #pragma unroll
        for (int ni = 0; ni < 4; ++ni) {
            #pragma unroll
            for (int rg = 0; rg < 4; ++rg) {
                int rowl = wn0 + ni * 16 + quad * 4 + rg;
                float xr = xsq_s[rowl];
                float best = 3.4e38f; int bk = 0;
                #pragma unroll
                for (int ki = 0; ki < 4; ++ki) {
                    int kl = wk0 + ki * 16 + lq;
                    float t = xr - acc[ni][ki][rg] * 6.103515625e-05f; // 2^-14
                    t += wsq_s[kl];
                    t += 1e-8f;
                    if (t < best) { best = t; bk = k0 + kl; }
                }
                unsigned u = __float_as_uint(best);
                u = (u & 0x80000000u) ? ~u : (u | 0x80000000u);
                unsigned long long p =
                    ((unsigned long long)u << 32) | (unsigned)bk;
                #pragma unroll
                for (int m = 1; m < 16; m <<= 1) {
                    unsigned long long o = __shfl_xor(p, m, 64);
                    if (o < p) p = o;
                }
                if (lq == 0) red[rowl][wave & 1] = p;
            }
        }
        __syncthreads();
        if (tid < 128) {
            unsigned long long a = red[tid][0], b = red[tid][1];
            atomicMin(&packed[n0 + tid], a < b ? a : b);
        }
    }
}

// ---------------- K5: combine -> indices, one-hot 1.0, counts ---------------
__global__ __launch_bounds__(256) void combine(
    const unsigned long long* __restrict__ packed,
    float* __restrict__ idxf, float* __restrict__ enc,
    float* __restrict__ counts)
{
    int n = blockIdx.x * 256 + threadIdx.x;
    unsigned k = (unsigned)(packed[n] & 0xFFFFFFFFu);
    idxf[n] = (float)k;
    enc[(size_t)n * K_CODES + k] = 1.0f;
    atomicAdd(&counts[k], 1.0f);
}

// ---------------- K6: gather -> quantized_st (NCHW) + per-block loss partial
__global__ __launch_bounds__(256) void quantize_loss(
    const float* __restrict__ x, const float* __restrict__ w,
    const float* __restrict__ idxf, float* __restrict__ outq,
    float* __restrict__ part)
{
    const int base4 = (blockIdx.x * 256 + threadIdx.x) * 4;
    float s = 0.f;
    #pragma unroll
    for (int i = 0; i < 4; ++i) {
        int e  = base4 + i * 1048576;      // NCHW element index (x4 aligned)
        int hw = e & 1023;
        int c  = (e >> 10) & 127;
        int b  = e >> 17;
        int n  = (b << 10) | hw;           // multiple of 4
        float4 xv = *(const float4*)(x + e);
        float4 kf = *(const float4*)(idxf + n);
        float q0 = w[(int)kf.x * DIM + c];
        float q1 = w[(int)kf.y * DIM + c];
        float q2 = w[(int)kf.z * DIM + c];
        float q3 = w[(int)kf.w * DIM + c];
        float4 df; df.x = q0 - xv.x; df.y = q1 - xv.y;
                   df.z = q2 - xv.z; df.w = q3 - xv.w;
        float4 o;  o.x = xv.x + df.x; o.y = xv.y + df.y;
                   o.z = xv.z + df.z; o.w = xv.w + df.w;
        *(float4*)(outq + e) = o;
        s = fmaf(df.x, df.x, s);
        s = fmaf(df.y, df.y, s);
        s = fmaf(df.z, df.z, s);
        s = fmaf(df.w, df.w, s);
    }
    #pragma unroll
    for (int o = 32; o > 0; o >>= 1) s += __shfl_down(s, o, 64);
    __shared__ float ls[4];
    if ((threadIdx.x & 63) == 0) ls[threadIdx.x >> 6] = s;
    __syncthreads();
    if (threadIdx.x == 0) part[blockIdx.x] = ls[0] + ls[1] + ls[2] + ls[3];
}

// ---------------- K7: loss (from partials) + perplexity ---------------------
__global__ __launch_bounds__(256) void finalize(
    const float* __restrict__ counts, const float* __restrict__ part,
    float* __restrict__ out)
{
    __shared__ float sh[512];
    float h = 0.f;
    for (int k = threadIdx.x; k < K_CODES; k += 256) {
        float p = counts[k] * (1.0f / N_FLAT);
        h += p * logf(p + 1e-10f);
    }
    float s = 0.f;
    for (int i = threadIdx.x; i < 1024; i += 256) s += part[i];
    sh[threadIdx.x] = h;
    sh[256 + threadIdx.x] = s;
    __syncthreads();
    #pragma unroll
    for (int st = 128; st > 0; st >>= 1) {
        if (threadIdx.x < st) {
            sh[threadIdx.x] += sh[threadIdx.x + st];
            sh[256 + threadIdx.x] += sh[256 + threadIdx.x + st];
        }
        __syncthreads();
    }
    if (threadIdx.x == 0) {
        float perp = expf(-sh[0]);
        float loss = 1.25f * (sh[256] / 4194304.0f);
        if (isnan(loss) || isinf(loss)) loss = 0.1f;
        out[OFF_LOSS] = loss;
        out[OFF_PERP] = perp;
    }
}

extern "C" void kernel_launch(void* const* d_in, const int* in_sizes, int n_in,
                              void* d_out, int out_size, void* d_ws, size_t ws_size,
                              hipStream_t stream) {
    const float* x = (const float*)d_in[0];   // [32,128,32,32] fp32 NCHW
    const float* w = (const float*)d_in[1];   // [4096,128] fp32
    float* out = (float*)d_out;
    char* ws = (char*)d_ws;

    unsigned long long* packed = (unsigned long long*)(ws + WS_PACKED);
    float* counts = (float*)(ws + WS_COUNTS);
    float* wsq    = (float*)(ws + WS_WSQ);
    float* xsq    = (float*)(ws + WS_XSQ);
    float* part   = (float*)(ws + WS_PART);
    _Float16* xhl = (_Float16*)(ws + WS_XHL);
    _Float16* whl = (_Float16*)(ws + WS_WHL);

    wsq_kernel<<<K_CODES / 4, 256, 0, stream>>>(w, wsq, counts);
    wplanes_kernel<<<K_CODES * 4 / 256, 256, 0, stream>>>(w, whl);
    xprep_kernel<<<N_FLAT / 64, 256, 0, stream>>>(x, xhl, xsq, packed);

    dim3 g2(256, 8);
    dist_argmin<<<g2, 256, 0, stream>>>(xhl, whl, wsq, xsq, packed,
                                        out + OFF_ENC);

    combine<<<N_FLAT / 256, 256, 0, stream>>>(packed, out + OFF_IDX,
                                              out + OFF_ENC, counts);

    quantize_loss<<<1024, 256, 0, stream>>>(x, w, out + OFF_IDX,
                                            out + OFF_Q, part);

    finalize<<<1, 256, 0, stream>>>(counts, part, out);
}